// Round 4
// baseline (3468.230 us; speedup 1.0000x reference)
//
#include <hip/hip_runtime.h>
#include <math.h>
#include <stdint.h>
#include <stddef.h>

// Problem dims (hard-coded per reference)
#define B_ 512
#define H_ 512
#define E_ 512
#define V_ 2048
#define IN_ 1024
#define LSTEPS 32
#define LP1 33

// JAX threefry mode: 1 = partitionable (JAX >= 0.4.36 default), 0 = original
#define TF_PARTITIONABLE 1

__device__ __forceinline__ void tf2x32(uint32_t k0, uint32_t k1,
                                       uint32_t x0, uint32_t x1,
                                       uint32_t& o0, uint32_t& o1) {
  uint32_t ks2 = k0 ^ k1 ^ 0x1BD11BDAu;
  x0 += k0; x1 += k1;
#define TFR(R) { x0 += x1; x1 = (x1 << (R)) | (x1 >> (32 - (R))); x1 ^= x0; }
  TFR(13) TFR(15) TFR(26) TFR(6)
  x0 += k1; x1 += ks2 + 1u;
  TFR(17) TFR(29) TFR(16) TFR(24)
  x0 += ks2; x1 += k0 + 2u;
  TFR(13) TFR(15) TFR(26) TFR(6)
  x0 += k0; x1 += k1 + 3u;
  TFR(17) TFR(29) TFR(16) TFR(24)
  x0 += k1; x1 += ks2 + 4u;
  TFR(13) TFR(15) TFR(26) TFR(6)
  x0 += ks2; x1 += k0 + 5u;
#undef TFR
  o0 = x0; o1 = x1;
}

__global__ void init_keys_kernel(uint32_t* __restrict__ sk) {
  uint32_t k0 = 0u, k1 = 1u;
  for (int t = 0; t < LSTEPS; t++) {
    uint32_t a0, a1, b0, b1;
#if TF_PARTITIONABLE
    tf2x32(k0, k1, 0u, 0u, a0, a1);
    tf2x32(k0, k1, 0u, 1u, b0, b1);
    sk[2 * t] = b0; sk[2 * t + 1] = b1;
    k0 = a0; k1 = a1;
#else
    tf2x32(k0, k1, 0u, 2u, a0, a1);
    tf2x32(k0, k1, 1u, 3u, b0, b1);
    sk[2 * t] = a1; sk[2 * t + 1] = b1;
    k0 = a0; k1 = b0;
#endif
  }
}

__global__ __launch_bounds__(256) void init_state_kernel(
    const float* __restrict__ sos, float* __restrict__ c, float* __restrict__ e) {
  int idx = blockIdx.x * 256 + threadIdx.x;
  if (idx < B_ * H_) {
    c[idx] = 0.0f;
    e[idx] = sos[idx & (E_ - 1)];
  }
}

__global__ __launch_bounds__(256) void eos_fill_kernel(
    float* __restrict__ o_seq, float* __restrict__ o_probs,
    float* __restrict__ o_logp, float* __restrict__ o_ent) {
  int b = blockIdx.x, tid = threadIdx.x;
  float* pr = o_probs + ((size_t)b * LP1 + LSTEPS) * V_;
  for (int v = tid; v < V_; v += 256) pr[v] = 1.0f;
  if (tid == 0) {
    o_seq[b * LP1 + LSTEPS] = 0.0f;
    o_logp[b * LP1 + LSTEPS] = 0.0f;
    o_ent[b * LP1 + LSTEPS] = 0.0f;
  }
}

// ---- async global->LDS staging helper (16B per lane, wave-uniform LDS base)
typedef __attribute__((address_space(1))) const void GASV;
typedef __attribute__((address_space(3))) void LASV;
__device__ __forceinline__ void gld16(const void* g, void* l) {
  __builtin_amdgcn_global_load_lds((GASV*)g, (LASV*)l, 16, 0, 0);
}

__device__ __forceinline__ float sigm(float x) { return 1.0f / (1.0f + expf(-x)); }

// Fused gates GEMM + LSTM cell, full-K (no split-K, no partials).
// Tile: 32 rows x 64 cols where the 64 cols = 4 gates x 16 h-cols (gate-interleaved
// so the cell epilogue is block-local). grid = (32 colstrips, 16 rowtiles), 256 thr.
// K = 1024: chunks 0..31 read A from e / B from w_ih; 32..63 from h_in / w_hh.
// Double-buffered LDS, staged entirely via global_load_lds width-16.
__global__ __launch_bounds__(256) void gates_cell_kernel(
    const float* __restrict__ e, const float* __restrict__ h_in,
    const float* __restrict__ w_ih, const float* __restrict__ w_hh,
    const float* __restrict__ b_ih, const float* __restrict__ b_hh,
    float* __restrict__ c, float* __restrict__ h_out) {
  __shared__ float lds[3072];   // As0[32][16]=512 | Bs0[16][64]=1024 | As1=512 | Bs1=1024
  const int AS0 = 0, BS0 = 512, AS1 = 1536, BS1 = 2048;
  int tid = threadIdx.x;
  int cs = blockIdx.x;          // col strip: h-cols [cs*16, cs*16+16) x 4 gates
  int r0 = blockIdx.y * 32;
  int w = tid >> 6, l = tid & 63;
  // A staging (waves 0,1 only): row w*16 + l/4, k-sub (l%4)*4
  int arow = w * 16 + (l >> 2);
  int akc = (l & 3) * 4;
  // B staging (all 4 waves): k-row w*4 + l/16; global col = gate*512 + cs*16 + (l%4)*4
  int bkrow = w * 4 + (l >> 4);
  int bgcol = ((l & 15) >> 2) * 512 + cs * 16 + (l & 3) * 4;
  int ty = tid >> 5, tx = tid & 31;   // micro-tile: rows ty*4..+3, cols tx*2..+1

  float acc[4][2] = {};

#define STAGEG(CH, ASB, BSB) {                                                   \
    int kc = (CH) << 4;                                                          \
    const float* Asrc = (kc < 512)                                               \
        ? (e + (size_t)(r0 + arow) * 512 + kc + akc)                             \
        : (h_in + (size_t)(r0 + arow) * 512 + (kc - 512) + akc);                 \
    if (tid < 128) gld16(Asrc, (char*)lds + (ASB) * 4 + w * 1024);               \
    const float* Bsrc = (kc < 512)                                               \
        ? (w_ih + (size_t)(kc + bkrow) * 2048 + bgcol)                           \
        : (w_hh + (size_t)(kc - 512 + bkrow) * 2048 + bgcol);                    \
    gld16(Bsrc, (char*)lds + (BSB) * 4 + w * 1024);                              \
  }

  STAGEG(0, AS0, BS0)
  for (int ch = 0; ch < 64; ch++) {
    __syncthreads();                 // drains vmcnt -> current buf ready
    if (ch + 1 < 64) {
      if ((ch + 1) & 1) STAGEG(ch + 1, AS1, BS1)
      else              STAGEG(ch + 1, AS0, BS0)
    }
    const float* As = lds + ((ch & 1) ? AS1 : AS0);
    const float* Bs = lds + ((ch & 1) ? BS1 : BS0);
#pragma unroll
    for (int kg = 0; kg < 4; kg++) {
      float4 a[4];
#pragma unroll
      for (int i = 0; i < 4; i++) a[i] = *(const float4*)&As[(ty * 4 + i) * 16 + kg * 4];
#pragma unroll
      for (int kk = 0; kk < 4; kk++) {
        float2 bb = *(const float2*)&Bs[(kg * 4 + kk) * 64 + tx * 2];
#pragma unroll
        for (int i = 0; i < 4; i++) {
          float av = ((const float*)&a[i])[kk];
          acc[i][0] += av * bb.x;
          acc[i][1] += av * bb.y;
        }
      }
    }
  }
#undef STAGEG

  // ---- cell epilogue via LDS gate-exchange (gtile[32][64] reuses lds[0..2047])
  __syncthreads();
#pragma unroll
  for (int i = 0; i < 4; i++)
    *(float2*)&lds[(ty * 4 + i) * 64 + tx * 2] = make_float2(acc[i][0], acc[i][1]);
  __syncthreads();

  int row = tid >> 3;            // 0..31
  int hc = (tid & 7) * 2;        // 0..14 (pair)
  int gcol = cs * 16 + hc;       // global h-col of the pair
  float2 ig = *(const float2*)&lds[row * 64 + 0 * 16 + hc];
  float2 fg = *(const float2*)&lds[row * 64 + 1 * 16 + hc];
  float2 gg = *(const float2*)&lds[row * 64 + 2 * 16 + hc];
  float2 og = *(const float2*)&lds[row * 64 + 3 * 16 + hc];
  ig.x += b_ih[gcol] + b_hh[gcol];
  ig.y += b_ih[gcol + 1] + b_hh[gcol + 1];
  fg.x += b_ih[512 + gcol] + b_hh[512 + gcol];
  fg.y += b_ih[512 + gcol + 1] + b_hh[512 + gcol + 1];
  gg.x += b_ih[1024 + gcol] + b_hh[1024 + gcol];
  gg.y += b_ih[1024 + gcol + 1] + b_hh[1024 + gcol + 1];
  og.x += b_ih[1536 + gcol] + b_hh[1536 + gcol];
  og.y += b_ih[1536 + gcol + 1] + b_hh[1536 + gcol + 1];
  size_t ci = (size_t)(r0 + row) * 512 + gcol;
  float2 cold = *(const float2*)&c[ci];
  float2 cn, hn;
  cn.x = sigm(fg.x) * cold.x + sigm(ig.x) * tanhf(gg.x);
  cn.y = sigm(fg.y) * cold.y + sigm(ig.y) * tanhf(gg.y);
  hn.x = sigm(og.x) * tanhf(cn.x);
  hn.y = sigm(og.y) * tanhf(cn.y);
  *(float2*)&c[ci] = cn;
  *(float2*)&h_out[ci] = hn;
}

// Plain full-K GEMM + bias: Z[32-row tile, 64-col tile] = A @ B + bias.
// grid = (Nout/64, M/32), 256 threads, same engine as gates kernel.
__global__ __launch_bounds__(256) void gemm_plain_bias(
    const float* __restrict__ A, int strideA,
    const float* __restrict__ Bm, const float* __restrict__ bias,
    float* __restrict__ Z, int Nout, int nch) {
  __shared__ float lds[3072];
  const int AS0 = 0, BS0 = 512, AS1 = 1536, BS1 = 2048;
  int tid = threadIdx.x;
  int n0 = blockIdx.x * 64;
  int r0 = blockIdx.y * 32;
  int w = tid >> 6, l = tid & 63;
  int arow = w * 16 + (l >> 2);
  int akc = (l & 3) * 4;
  int bkrow = w * 4 + (l >> 4);
  int bgcol = n0 + (l & 15) * 4;
  int ty = tid >> 5, tx = tid & 31;

  float acc[4][2] = {};

#define STAGEP(CH, ASB, BSB) {                                                   \
    int kc = (CH) << 4;                                                          \
    if (tid < 128)                                                               \
      gld16(A + (size_t)(r0 + arow) * strideA + kc + akc,                        \
            (char*)lds + (ASB) * 4 + w * 1024);                                  \
    gld16(Bm + (size_t)(kc + bkrow) * Nout + bgcol,                              \
          (char*)lds + (BSB) * 4 + w * 1024);                                    \
  }

  STAGEP(0, AS0, BS0)
  for (int ch = 0; ch < nch; ch++) {
    __syncthreads();
    if (ch + 1 < nch) {
      if ((ch + 1) & 1) STAGEP(ch + 1, AS1, BS1)
      else              STAGEP(ch + 1, AS0, BS0)
    }
    const float* As = lds + ((ch & 1) ? AS1 : AS0);
    const float* Bs = lds + ((ch & 1) ? BS1 : BS0);
#pragma unroll
    for (int kg = 0; kg < 4; kg++) {
      float4 a[4];
#pragma unroll
      for (int i = 0; i < 4; i++) a[i] = *(const float4*)&As[(ty * 4 + i) * 16 + kg * 4];
#pragma unroll
      for (int kk = 0; kk < 4; kk++) {
        float2 bb = *(const float2*)&Bs[(kg * 4 + kk) * 64 + tx * 2];
#pragma unroll
        for (int i = 0; i < 4; i++) {
          float av = ((const float*)&a[i])[kk];
          acc[i][0] += av * bb.x;
          acc[i][1] += av * bb.y;
        }
      }
    }
  }
#undef STAGEP

  int col = n0 + tx * 2;
  float2 bv = *(const float2*)&bias[col];
#pragma unroll
  for (int i = 0; i < 4; i++) {
    float2 o;
    o.x = acc[i][0] + bv.x;
    o.y = acc[i][1] + bv.y;
    *(float2*)&Z[(size_t)(r0 + ty * 4 + i) * Nout + col] = o;
  }
}

// Per-row: log_softmax, entropy, probs write, threefry gumbel argmax sample,
// logp gather, embedding gather. One block of 512 threads per row; 4 logits/thread.
__global__ __launch_bounds__(512) void sample_step_kernel(
    const float* __restrict__ z, const float* __restrict__ out_b_unused,
    const uint32_t* __restrict__ skv,
    const float* __restrict__ embedding, float* __restrict__ e,
    float* __restrict__ o_seq, float* __restrict__ o_probs,
    float* __restrict__ o_logp, float* __restrict__ o_ent, int t) {
  __shared__ float zs[V_];
  __shared__ float rmax[8], rsum[8], rps[8], rav[8];
  __shared__ int rai[8];
  int tid = threadIdx.x, b = blockIdx.x;
  int wid = tid >> 6;
  float4 za = *(const float4*)(z + (size_t)b * V_ + tid * 4);
  float zv[4] = {za.x, za.y, za.z, za.w};
  *(float4*)&zs[tid * 4] = za;

  float m = fmaxf(fmaxf(zv[0], zv[1]), fmaxf(zv[2], zv[3]));
  for (int off = 32; off; off >>= 1) m = fmaxf(m, __shfl_xor(m, off));
  if ((tid & 63) == 0) rmax[wid] = m;
  __syncthreads();
#pragma unroll
  for (int w2 = 0; w2 < 8; w2++) m = fmaxf(m, rmax[w2]);

  float sh[4];
  float ssum = 0.f;
#pragma unroll
  for (int i = 0; i < 4; i++) { sh[i] = zv[i] - m; ssum += expf(sh[i]); }
  for (int off = 32; off; off >>= 1) ssum += __shfl_xor(ssum, off);
  if ((tid & 63) == 0) rsum[wid] = ssum;
  __syncthreads();
  float S = 0.f;
#pragma unroll
  for (int w2 = 0; w2 < 8; w2++) S += rsum[w2];
  float ls = logf(S);

  uint32_t sk0 = skv[2 * t], sk1 = skv[2 * t + 1];
  float psum = 0.f;
  float best = -INFINITY;
  int bi = 0;
  float pv[4];
#pragma unroll
  for (int i = 0; i < 4; i++) {
    float s = sh[i] - ls;
    float p = expf(s);
    pv[i] = p;
    psum += p * s;
    int v = tid * 4 + i;
    uint32_t o0, o1, bits;
#if TF_PARTITIONABLE
    uint32_t j = (uint32_t)(b * V_ + v);
    tf2x32(sk0, sk1, 0u, j, o0, o1);
    bits = o0 ^ o1;
#else
    uint32_t j = (uint32_t)(b * V_ + v);
    const uint32_t n2 = (uint32_t)(B_ * V_ / 2);
    if (j < n2) { tf2x32(sk0, sk1, j, j + n2, o0, o1); bits = o0; }
    else       { tf2x32(sk0, sk1, j - n2, j, o0, o1); bits = o1; }
#endif
    float f = __uint_as_float((bits >> 9) | 0x3f800000u) - 1.0f;
    float u = fmaxf(f, 1.17549435e-38f);
    float g = -logf(-logf(u));
    float a = s + g;
    if (a > best) { best = a; bi = v; }
  }
  float* prw = o_probs + ((size_t)b * LP1 + t) * V_ + tid * 4;
  *(float4*)prw = make_float4(pv[0], pv[1], pv[2], pv[3]);

  for (int off = 32; off; off >>= 1) psum += __shfl_xor(psum, off);
  for (int off = 32; off; off >>= 1) {
    float ov = __shfl_xor(best, off);
    int oi = __shfl_xor(bi, off);
    if (ov > best || (ov == best && oi < bi)) { best = ov; bi = oi; }
  }
  if ((tid & 63) == 0) { rps[wid] = psum; rav[wid] = best; rai[wid] = bi; }
  __syncthreads();
  float ent = 0.f;
#pragma unroll
  for (int w2 = 0; w2 < 8; w2++) ent += rps[w2];
  ent = -ent;
  float bv2 = rav[0]; int sym = rai[0];
#pragma unroll
  for (int w2 = 1; w2 < 8; w2++) {
    if (rav[w2] > bv2 || (rav[w2] == bv2 && rai[w2] < sym)) { bv2 = rav[w2]; sym = rai[w2]; }
  }
  // gather next embedding (E_=512 floats = 128 float4)
  if (tid < 128) {
    ((float4*)(e + (size_t)b * E_))[tid] = ((const float4*)(embedding + (size_t)sym * E_))[tid];
  }
  if (tid == 0) {
    float s_sym = (zs[sym] - m) - ls;
    o_seq[b * LP1 + t] = (float)sym;
    o_logp[b * LP1 + t] = s_sym;
    o_ent[b * LP1 + t] = ent;
  }
}

extern "C" void kernel_launch(void* const* d_in, const int* in_sizes, int n_in,
                              void* d_out, int out_size, void* d_ws, size_t ws_size,
                              hipStream_t stream) {
  (void)in_sizes; (void)n_in; (void)out_size; (void)ws_size;
  const float* x     = (const float*)d_in[0];
  const float* agw   = (const float*)d_in[1];
  const float* agb   = (const float*)d_in[2];
  const float* sos   = (const float*)d_in[3];
  const float* emb   = (const float*)d_in[4];
  const float* w_ih  = (const float*)d_in[5];
  const float* w_hh  = (const float*)d_in[6];
  const float* b_ih  = (const float*)d_in[7];
  const float* b_hh  = (const float*)d_in[8];
  const float* out_w = (const float*)d_in[9];
  const float* out_b = (const float*)d_in[10];

  char* w = (char*)d_ws;
  uint32_t* sk = (uint32_t*)w;                                // 256 B used
  float* e  = (float*)(w + 1024);                             // 1 MB
  float* hA = (float*)(w + 1024 + 1 * 1048576);               // 1 MB
  float* hB = (float*)(w + 1024 + 2 * 1048576);               // 1 MB
  float* c  = (float*)(w + 1024 + 3 * 1048576);               // 1 MB
  float* z  = (float*)(w + 1024 + 4 * 1048576);               // 4 MB

  float* out = (float*)d_out;
  float* o_seq   = out;                                       // [512,33]
  float* o_probs = out + (size_t)B_ * LP1;                    // [512,33,2048]
  float* o_logp  = o_probs + (size_t)B_ * LP1 * V_;           // [512,33]
  float* o_ent   = o_logp + (size_t)B_ * LP1;                 // [512,33]

  init_keys_kernel<<<1, 1, 0, stream>>>(sk);
  init_state_kernel<<<(B_ * H_ + 255) / 256, 256, 0, stream>>>(sos, c, e);
  eos_fill_kernel<<<B_, 256, 0, stream>>>(o_seq, o_probs, o_logp, o_ent);

  // h0 = x @ agent_w + agent_b  (M=512, N=512, K=1024 -> nch=64)
  gemm_plain_bias<<<dim3(H_ / 64, B_ / 32), 256, 0, stream>>>(
      x, IN_, agw, agb, hA, H_, IN_ / 16);

  for (int t = 0; t < LSTEPS; t++) {
    float* hin  = (t & 1) ? hB : hA;
    float* hout = (t & 1) ? hA : hB;
    // gates + cell fused (full K = 1024)
    gates_cell_kernel<<<dim3(32, 16), 256, 0, stream>>>(
        e, hin, w_ih, w_hh, b_ih, b_hh, c, hout);
    // logits = h @ out_w + out_b  (K=512 -> nch=32)
    gemm_plain_bias<<<dim3(V_ / 64, B_ / 32), 256, 0, stream>>>(
        hout, H_, out_w, out_b, z, V_, H_ / 16);
    sample_step_kernel<<<B_, 512, 0, stream>>>(
        z, out_b, sk, emb, e, o_seq, o_probs, o_logp, o_ent, t);
  }
}